// Round 1
// baseline (585.348 us; speedup 1.0000x reference)
//
#include <hip/hip_runtime.h>

#define B_ 8
#define N_ 2048
#define D_ 1024
#define M_ (B_*N_)          // 16384 rows
#define SEGS 32
#define EPB (4096/SEGS)     // 128 events per segment

typedef __attribute__((ext_vector_type(8))) short short8;
typedef __attribute__((ext_vector_type(4))) float floatx4;

__device__ __forceinline__ ushort f2bf(float f) {
  unsigned u = __builtin_bit_cast(unsigned, f);
  return (ushort)((u + 0x7fffu + ((u >> 16) & 1u)) >> 16);
}
__device__ __forceinline__ float bf2f(ushort u) {
  return __builtin_bit_cast(float, ((unsigned)u) << 16);
}
__device__ __forceinline__ void gload16(const void* g, void* l) {
  __builtin_amdgcn_global_load_lds(
      (const __attribute__((address_space(1))) unsigned*)g,
      (__attribute__((address_space(3))) unsigned*)l, 16, 0, 0);
}
__device__ __forceinline__ float sig4(float h) {
  // sigmoid(4*(h-1))
  return 1.0f / (1.0f + __expf(4.0f - 4.0f*h));
}

// ---------------- conversions ----------------
__global__ __launch_bounds__(256) void conv_x_k(const float4* __restrict__ x,
                                                ushort4* __restrict__ o) {
  int i = blockIdx.x * 256 + threadIdx.x;
  float4 f = x[i];
  ushort4 u;
  u.x = f2bf(f.x); u.y = f2bf(f.y); u.z = f2bf(f.z); u.w = f2bf(f.w);
  o[i] = u;
}

__global__ __launch_bounds__(256) void transpose_k(const float* __restrict__ W,
                                                   ushort* __restrict__ WT) {
  __shared__ float tile[32][33];
  int tx = threadIdx.x, ty = threadIdx.y;
  int x = blockIdx.x * 32 + tx;
  int y = blockIdx.y * 32 + ty;
#pragma unroll
  for (int j = 0; j < 32; j += 8)
    tile[ty + j][tx] = W[(size_t)(y + j) * D_ + x];
  __syncthreads();
  int x2 = blockIdx.y * 32 + tx;
  int y2 = blockIdx.x * 32 + ty;
#pragma unroll
  for (int j = 0; j < 32; j += 8)
    WT[(size_t)(y2 + j) * D_ + x2] = f2bf(tile[tx][ty + j]);
}

// ---------------- GEMM: C[M,1024] = A[M,1024] @ Bt[1024,1024]^T ----------------
// MODE 0: BN+sigmoid -> bf16 out (V)
// MODE 1: BN+sigmoid -> row-sum atomics (Q/K means)
// MODE 2: + bias -> fp32 out (final)
template<int MODE>
__global__ __launch_bounds__(256) void gemm_k(
    const ushort* __restrict__ A, const ushort* __restrict__ Bt,
    const float* __restrict__ gg, const float* __restrict__ bb,
    const float* __restrict__ mmn, const float* __restrict__ vvn,
    float* __restrict__ rowsum, ushort* __restrict__ outB,
    float* __restrict__ outF, const float* __restrict__ bo)
{
  constexpr int K = D_;
  constexpr int NN = D_;
  __shared__ ushort As[128 * 32];
  __shared__ ushort Bs[128 * 32];
  const int t = threadIdx.x;
  const int lane = t & 63, wid = t >> 6;
  const int quad = lane >> 4, l15 = lane & 15;
  const int wm = wid >> 1, wn = wid & 1;
  const int tileM = blockIdx.y * 128, tileN = blockIdx.x * 128;

  floatx4 acc[4][4];
#pragma unroll
  for (int i = 0; i < 4; i++)
#pragma unroll
    for (int j = 0; j < 4; j++) acc[i][j] = (floatx4){0.f, 0.f, 0.f, 0.f};

  const ushort* Ab = A + (size_t)tileM * K;
  const ushort* Bb = Bt + (size_t)tileN * K;

  for (int k0 = 0; k0 < K; k0 += 32) {
    __syncthreads();
#pragma unroll
    for (int r = 0; r < 2; r++) {
      int li = r * 256 + t;
      int row = li >> 2, kc = li & 3;
      gload16(Ab + (size_t)row * K + k0 + kc * 8, (char*)As + li * 16);
      gload16(Bb + (size_t)row * K + k0 + kc * 8, (char*)Bs + li * 16);
    }
    __syncthreads();
    short8 af[4], bfr[4];
#pragma unroll
    for (int tm = 0; tm < 4; tm++)
      af[tm] = *(const short8*)(As + (wm * 64 + tm * 16 + l15) * 32 + quad * 8);
#pragma unroll
    for (int tn = 0; tn < 4; tn++)
      bfr[tn] = *(const short8*)(Bs + (wn * 64 + tn * 16 + l15) * 32 + quad * 8);
#pragma unroll
    for (int tm = 0; tm < 4; tm++)
#pragma unroll
      for (int tn = 0; tn < 4; tn++)
        acc[tm][tn] = __builtin_amdgcn_mfma_f32_16x16x32_bf16(af[tm], bfr[tn], acc[tm][tn], 0, 0, 0);
  }

  if constexpr (MODE == 2) {
#pragma unroll
    for (int tn = 0; tn < 4; tn++) {
      int col = tileN + wn * 64 + tn * 16 + l15;
      float bias = bo[col];
#pragma unroll
      for (int tm = 0; tm < 4; tm++) {
        int row0 = tileM + wm * 64 + tm * 16 + quad * 4;
#pragma unroll
        for (int r = 0; r < 4; r++)
          outF[(size_t)(row0 + r) * NN + col] = acc[tm][tn][r] + bias;
      }
    }
  } else if constexpr (MODE == 0) {
#pragma unroll
    for (int tn = 0; tn < 4; tn++) {
      int col = tileN + wn * 64 + tn * 16 + l15;
      float sc = gg[col] * rsqrtf(vvn[col] + 1e-5f);
      float sh = bb[col] - mmn[col] * sc;
#pragma unroll
      for (int tm = 0; tm < 4; tm++) {
        int row0 = tileM + wm * 64 + tm * 16 + quad * 4;
#pragma unroll
        for (int r = 0; r < 4; r++)
          outB[(size_t)(row0 + r) * NN + col] = f2bf(sig4(acc[tm][tn][r] * sc + sh));
      }
    }
  } else {  // MODE 1: row-sums of sigmoid
    float rs[4][4];
#pragma unroll
    for (int tm = 0; tm < 4; tm++)
#pragma unroll
      for (int r = 0; r < 4; r++) rs[tm][r] = 0.f;
#pragma unroll
    for (int tn = 0; tn < 4; tn++) {
      int col = tileN + wn * 64 + tn * 16 + l15;
      float sc = gg[col] * rsqrtf(vvn[col] + 1e-5f);
      float sh = bb[col] - mmn[col] * sc;
#pragma unroll
      for (int tm = 0; tm < 4; tm++)
#pragma unroll
        for (int r = 0; r < 4; r++)
          rs[tm][r] += sig4(acc[tm][tn][r] * sc + sh);
    }
#pragma unroll
    for (int off = 1; off < 16; off <<= 1)
#pragma unroll
      for (int tm = 0; tm < 4; tm++)
#pragma unroll
        for (int r = 0; r < 4; r++)
          rs[tm][r] += __shfl_xor(rs[tm][r], off, 64);
    if (l15 == 0) {
#pragma unroll
      for (int tm = 0; tm < 4; tm++) {
        int row0 = tileM + wm * 64 + tm * 16 + quad * 4;
#pragma unroll
        for (int r = 0; r < 4; r++)
          atomicAdd(&rowsum[row0 + r], rs[tm][r]);
      }
    }
  }
}

// ---------------- event sort (bitonic, per batch) ----------------
// ascending by (value, tag): keys (tag bit 0) before queries (tag bit 1) on ties
__global__ __launch_bounds__(1024) void sort_events_k(
    const float* __restrict__ rsQ, const float* __restrict__ rsK,
    int* __restrict__ evt_tag, float* __restrict__ evt_wa, float* __restrict__ evt_wd)
{
  __shared__ float sv[4096];
  __shared__ unsigned st[4096];
  int b = blockIdx.x;
  int t = threadIdx.x;
  for (int i = t; i < 4096; i += 1024) {
    if (i < 2048) {
      float tq = 1.0f - rsQ[b * N_ + i] * (1.0f / 1024.0f);
      sv[i] = tq; st[i] = (unsigned)i | 0x10000u;  // query
    } else {
      int j = i - 2048;
      float tk = 1.0f - rsK[b * N_ + j] * (1.0f / 1024.0f);
      sv[i] = tk; st[i] = (unsigned)j;             // key
    }
  }
  __syncthreads();
  for (int ksz = 2; ksz <= 4096; ksz <<= 1) {
    for (int j = ksz >> 1; j > 0; j >>= 1) {
      for (int i = t; i < 4096; i += 1024) {
        int ixj = i ^ j;
        if (ixj > i) {
          bool up = ((i & ksz) == 0);
          float v1 = sv[i], v2 = sv[ixj];
          unsigned t1 = st[i], t2 = st[ixj];
          bool gt = (v1 > v2) || (v1 == v2 && (t1 & 0x10000u) > (t2 & 0x10000u));
          if (gt == up) { sv[i] = v2; sv[ixj] = v1; st[i] = t2; st[ixj] = t1; }
        }
      }
      __syncthreads();
    }
  }
  for (int i = t; i < 4096; i += 1024) {
    float v = sv[i];
    unsigned tg = st[i];
    bool isq = (tg & 0x10000u) != 0;
    // keys: wa=e^{2tk} (asc weight), wd=e^{-2tk} (desc weight)
    // queries: wa=e^{-2tq} (asc mult), wd=e^{2tq} (desc mult)
    evt_tag[b * 4096 + i] = (int)tg;
    evt_wa[b * 4096 + i] = isq ? expf(-2.0f * v) : expf(2.0f * v);
    evt_wd[b * 4096 + i] = isq ? expf(2.0f * v) : expf(-2.0f * v);
  }
}

// ---------------- segment totals ----------------
__global__ __launch_bounds__(256) void seg_tot_k(
    const int* __restrict__ evt_tag, const float* __restrict__ evt_wa,
    const float* __restrict__ evt_wd, const ushort* __restrict__ Vb,
    float* __restrict__ totWA, float* __restrict__ totWD, float* __restrict__ totP)
{
  int b = blockIdx.z, seg = blockIdx.y, chunk = blockIdx.x;
  int t = threadIdx.x;
  int c = chunk * 512 + t * 2;
  float wa0 = 0, wa1 = 0, wd0 = 0, wd1 = 0, p0 = 0, p1 = 0;
  int e0 = b * 4096 + seg * EPB;
  for (int e = 0; e < EPB; e++) {
    int tg = evt_tag[e0 + e];
    if (tg & 0x10000) continue;  // query
    int j = tg & 0xFFFF;
    unsigned raw = *(const unsigned*)(Vb + ((size_t)b * N_ + j) * D_ + c);
    float v0 = bf2f((ushort)(raw & 0xffffu)), v1 = bf2f((ushort)(raw >> 16));
    float wa = evt_wa[e0 + e], wd = evt_wd[e0 + e];
    wa0 += wa * v0; wa1 += wa * v1;
    wd0 += wd * v0; wd1 += wd * v1;
    p0 += v0; p1 += v1;
  }
  size_t o = ((size_t)b * SEGS + seg) * D_ + c;
  totWA[o] = wa0; totWA[o + 1] = wa1;
  totWD[o] = wd0; totWD[o + 1] = wd1;
  totP[o]  = p0;  totP[o + 1]  = p1;
}

// ---------------- ascending scan: low-side contribution ----------------
__global__ __launch_bounds__(256) void scan_asc_k(
    const int* __restrict__ evt_tag, const float* __restrict__ evt_wa,
    const ushort* __restrict__ Vb, const float* __restrict__ totWA,
    const float* __restrict__ totP, float* __restrict__ AVpart)
{
  int b = blockIdx.z, seg = blockIdx.y, chunk = blockIdx.x;
  int t = threadIdx.x;
  int c = chunk * 512 + t * 2;
  float s0 = 0, s1 = 0, p0 = 0, p1 = 0;
  for (int s = 0; s < seg; s++) {
    size_t o = ((size_t)b * SEGS + s) * D_ + c;
    s0 += totWA[o]; s1 += totWA[o + 1];
    p0 += totP[o];  p1 += totP[o + 1];
  }
  int e0 = b * 4096 + seg * EPB;
  for (int e = 0; e < EPB; e++) {
    int tg = evt_tag[e0 + e];
    float w = evt_wa[e0 + e];
    int idx = tg & 0xFFFF;
    if (tg & 0x10000) {  // query: emit 0.9*(Plow - e^{-2tq}*SlowW)
      size_t o = ((size_t)b * N_ + idx) * D_ + c;
      AVpart[o]     = 0.9f * (p0 - w * s0);
      AVpart[o + 1] = 0.9f * (p1 - w * s1);
    } else {
      unsigned raw = *(const unsigned*)(Vb + ((size_t)b * N_ + idx) * D_ + c);
      float v0 = bf2f((ushort)(raw & 0xffffu)), v1 = bf2f((ushort)(raw >> 16));
      s0 += w * v0; s1 += w * v1;
      p0 += v0;     p1 += v1;
    }
  }
}

// ---------------- descending scan: high-side contribution + finalize ----------------
__global__ __launch_bounds__(256) void scan_desc_k(
    const int* __restrict__ evt_tag, const float* __restrict__ evt_wd,
    const ushort* __restrict__ Vb, const float* __restrict__ totWD,
    const float* __restrict__ totP, const float* __restrict__ AVpart,
    ushort* __restrict__ AVb)
{
  int b = blockIdx.z, seg = blockIdx.y, chunk = blockIdx.x;
  int t = threadIdx.x;
  int c = chunk * 512 + t * 2;
  float s0 = 0, s1 = 0, p0 = 0, p1 = 0;
  for (int s = seg + 1; s < SEGS; s++) {
    size_t o = ((size_t)b * SEGS + s) * D_ + c;
    s0 += totWD[o]; s1 += totWD[o + 1];
    p0 += totP[o];  p1 += totP[o + 1];
  }
  int e0 = b * 4096 + seg * EPB;
  for (int e = EPB - 1; e >= 0; e--) {
    int tg = evt_tag[e0 + e];
    float w = evt_wd[e0 + e];
    int idx = tg & 0xFFFF;
    if (tg & 0x10000) {  // query: add 0.9*(Phigh + e^{2tq}*ShighW), write bf16
      size_t o = ((size_t)b * N_ + idx) * D_ + c;
      float r0 = AVpart[o]     + 0.9f * (p0 + w * s0);
      float r1 = AVpart[o + 1] + 0.9f * (p1 + w * s1);
      AVb[o] = f2bf(r0); AVb[o + 1] = f2bf(r1);
    } else {
      unsigned raw = *(const unsigned*)(Vb + ((size_t)b * N_ + idx) * D_ + c);
      float v0 = bf2f((ushort)(raw & 0xffffu)), v1 = bf2f((ushort)(raw >> 16));
      s0 += w * v0; s1 += w * v1;
      p0 += v0;     p1 += v1;
    }
  }
}

extern "C" void kernel_launch(void* const* d_in, const int* in_sizes, int n_in,
                              void* d_out, int out_size, void* d_ws, size_t ws_size,
                              hipStream_t stream) {
  (void)in_sizes; (void)n_in; (void)out_size; (void)ws_size;
  const float* x  = (const float*)d_in[0];
  const float* Wq = (const float*)d_in[1];
  const float* gq = (const float*)d_in[2];
  const float* bq = (const float*)d_in[3];
  const float* mq = (const float*)d_in[4];
  const float* vq = (const float*)d_in[5];
  const float* Wk = (const float*)d_in[6];
  const float* gk = (const float*)d_in[7];
  const float* bk = (const float*)d_in[8];
  const float* mk = (const float*)d_in[9];
  const float* vk = (const float*)d_in[10];
  const float* Wv = (const float*)d_in[11];
  const float* gv = (const float*)d_in[12];
  const float* bv = (const float*)d_in[13];
  const float* mv = (const float*)d_in[14];
  const float* vv = (const float*)d_in[15];
  const float* Wo = (const float*)d_in[16];
  const float* bo = (const float*)d_in[17];

  char* p = (char*)d_ws;
  auto alloc = [&](size_t n) { char* r = p; p += n; return r; };
  ushort* x16  = (ushort*)alloc((size_t)M_ * D_ * 2);
  ushort* Vb   = (ushort*)alloc((size_t)M_ * D_ * 2);
  ushort* AVb  = (ushort*)alloc((size_t)M_ * D_ * 2);
  ushort* WqT  = (ushort*)alloc((size_t)D_ * D_ * 2);
  ushort* WkT  = (ushort*)alloc((size_t)D_ * D_ * 2);
  ushort* WvT  = (ushort*)alloc((size_t)D_ * D_ * 2);
  ushort* WoT  = (ushort*)alloc((size_t)D_ * D_ * 2);
  float*  rsQ  = (float*)alloc((size_t)M_ * 4);
  float*  rsK  = (float*)alloc((size_t)M_ * 4);
  int*    evt_tag = (int*)alloc((size_t)B_ * 4096 * 4);
  float*  evt_wa  = (float*)alloc((size_t)B_ * 4096 * 4);
  float*  evt_wd  = (float*)alloc((size_t)B_ * 4096 * 4);
  float*  totWA   = (float*)alloc((size_t)B_ * SEGS * D_ * 4);
  float*  totWD   = (float*)alloc((size_t)B_ * SEGS * D_ * 4);
  float*  totP    = (float*)alloc((size_t)B_ * SEGS * D_ * 4);

  // zero the row-sum accumulators (rsQ, rsK are adjacent)
  hipMemsetAsync(rsQ, 0, (size_t)2 * M_ * 4, stream);

  conv_x_k<<<(M_ * D_) / 1024, 256, 0, stream>>>((const float4*)x, (ushort4*)x16);
  dim3 tb(32, 8), tg(32, 32);
  transpose_k<<<tg, tb, 0, stream>>>(Wq, WqT);
  transpose_k<<<tg, tb, 0, stream>>>(Wk, WkT);
  transpose_k<<<tg, tb, 0, stream>>>(Wv, WvT);
  transpose_k<<<tg, tb, 0, stream>>>(Wo, WoT);

  dim3 gg(D_ / 128, M_ / 128);
  gemm_k<1><<<gg, 256, 0, stream>>>(x16, WqT, gq, bq, mq, vq, rsQ, nullptr, nullptr, nullptr);
  gemm_k<1><<<gg, 256, 0, stream>>>(x16, WkT, gk, bk, mk, vk, rsK, nullptr, nullptr, nullptr);
  gemm_k<0><<<gg, 256, 0, stream>>>(x16, WvT, gv, bv, mv, vv, nullptr, Vb, nullptr, nullptr);

  sort_events_k<<<B_, 1024, 0, stream>>>(rsQ, rsK, evt_tag, evt_wa, evt_wd);

  dim3 sg(2, SEGS, B_);
  seg_tot_k<<<sg, 256, 0, stream>>>(evt_tag, evt_wa, evt_wd, Vb, totWA, totWD, totP);
  scan_asc_k<<<sg, 256, 0, stream>>>(evt_tag, evt_wa, Vb, totWA, totP, (float*)d_out);
  scan_desc_k<<<sg, 256, 0, stream>>>(evt_tag, evt_wd, Vb, totWD, totP, (const float*)d_out, AVb);

  gemm_k<2><<<gg, 256, 0, stream>>>(AVb, WoT, nullptr, nullptr, nullptr, nullptr, nullptr, nullptr, (float*)d_out, bo);
}

// Round 2
// 527.376 us; speedup vs baseline: 1.1099x; 1.1099x over previous
//
#include <hip/hip_runtime.h>

#define B_ 8
#define N_ 2048
#define D_ 1024
#define M_ (B_*N_)          // 16384 rows
#define SEGS 32
#define EPB (4096/SEGS)     // 128 events per segment

typedef __attribute__((ext_vector_type(8))) short short8;
typedef __attribute__((ext_vector_type(4))) float floatx4;

__device__ __forceinline__ ushort f2bf(float f) {
  unsigned u = __builtin_bit_cast(unsigned, f);
  return (ushort)((u + 0x7fffu + ((u >> 16) & 1u)) >> 16);
}
__device__ __forceinline__ float bf2f(ushort u) {
  return __builtin_bit_cast(float, ((unsigned)u) << 16);
}
__device__ __forceinline__ void gload16(const void* g, void* l) {
  __builtin_amdgcn_global_load_lds(
      (const __attribute__((address_space(1))) unsigned*)g,
      (__attribute__((address_space(3))) unsigned*)l, 16, 0, 0);
}
__device__ __forceinline__ float sig4(float h) {
  // sigmoid(4*(h-1))
  return 1.0f / (1.0f + __expf(4.0f - 4.0f*h));
}

// ---------------- conversions ----------------
__global__ __launch_bounds__(256) void conv_x_k(const float4* __restrict__ x,
                                                ushort4* __restrict__ o) {
  int i = blockIdx.x * 256 + threadIdx.x;
  float4 f = x[i];
  ushort4 u;
  u.x = f2bf(f.x); u.y = f2bf(f.y); u.z = f2bf(f.z); u.w = f2bf(f.w);
  o[i] = u;
}

// all 4 weight transposes in one launch; z selects the matrix
__global__ __launch_bounds__(256) void transpose_k(
    const float* __restrict__ Wq, const float* __restrict__ Wk,
    const float* __restrict__ Wv, const float* __restrict__ Wo,
    ushort* __restrict__ W3T, ushort* __restrict__ WoT) {
  __shared__ float tile[32][33];
  int z = blockIdx.z;
  const float* W = (z == 0) ? Wq : (z == 1) ? Wk : (z == 2) ? Wv : Wo;
  ushort* WT = (z < 3) ? (W3T + (size_t)z * D_ * D_) : WoT;
  int tx = threadIdx.x, ty = threadIdx.y;
  int x = blockIdx.x * 32 + tx;
  int y = blockIdx.y * 32 + ty;
#pragma unroll
  for (int j = 0; j < 32; j += 8)
    tile[ty + j][tx] = W[(size_t)(y + j) * D_ + x];
  __syncthreads();
  int x2 = blockIdx.y * 32 + tx;
  int y2 = blockIdx.x * 32 + ty;
#pragma unroll
  for (int j = 0; j < 32; j += 8)
    WT[(size_t)(y2 + j) * D_ + x2] = f2bf(tile[tx][ty + j]);
}

// ---------------- shared GEMM mainloop: 128x128 tile, BK=32 ----------------
__device__ __forceinline__ void gemm_mainloop(
    const ushort* __restrict__ Ab, const ushort* __restrict__ Bb,
    ushort* As, ushort* Bs, int t, int wm, int wn, int l15, int quad,
    floatx4 acc[4][4])
{
  for (int k0 = 0; k0 < D_; k0 += 32) {
    __syncthreads();
#pragma unroll
    for (int r = 0; r < 2; r++) {
      int li = r * 256 + t;
      int row = li >> 2, kc = li & 3;
      gload16(Ab + (size_t)row * D_ + k0 + kc * 8, (char*)As + li * 16);
      gload16(Bb + (size_t)row * D_ + k0 + kc * 8, (char*)Bs + li * 16);
    }
    __syncthreads();
    short8 af[4], bfr[4];
#pragma unroll
    for (int tm = 0; tm < 4; tm++)
      af[tm] = *(const short8*)(As + (wm * 64 + tm * 16 + l15) * 32 + quad * 8);
#pragma unroll
    for (int tn = 0; tn < 4; tn++)
      bfr[tn] = *(const short8*)(Bs + (wn * 64 + tn * 16 + l15) * 32 + quad * 8);
#pragma unroll
    for (int tm = 0; tm < 4; tm++)
#pragma unroll
      for (int tn = 0; tn < 4; tn++)
        acc[tm][tn] = __builtin_amdgcn_mfma_f32_16x16x32_bf16(af[tm], bfr[tn], acc[tm][tn], 0, 0, 0);
  }
}

// ---------------- fused QKV GEMM: z=0 Q-rowsum, z=1 K-rowsum, z=2 V-store ----
__global__ __launch_bounds__(256) void gemm_qkv_k(
    const ushort* __restrict__ A, const ushort* __restrict__ W3T,
    const float* __restrict__ gq, const float* __restrict__ bq,
    const float* __restrict__ mq, const float* __restrict__ vq,
    const float* __restrict__ gk, const float* __restrict__ bk,
    const float* __restrict__ mk, const float* __restrict__ vk,
    const float* __restrict__ gv, const float* __restrict__ bv,
    const float* __restrict__ mv, const float* __restrict__ vv,
    float* __restrict__ rsQ, float* __restrict__ rsK, ushort* __restrict__ Vb)
{
  __shared__ ushort As[128 * 32];
  __shared__ ushort Bs[128 * 32];
  const int t = threadIdx.x;
  const int lane = t & 63, wid = t >> 6;
  const int quad = lane >> 4, l15 = lane & 15;
  const int wm = wid >> 1, wn = wid & 1;
  const int tileM = blockIdx.y * 128, tileN = blockIdx.x * 128;
  const int z = blockIdx.z;

  floatx4 acc[4][4];
#pragma unroll
  for (int i = 0; i < 4; i++)
#pragma unroll
    for (int j = 0; j < 4; j++) acc[i][j] = (floatx4){0.f, 0.f, 0.f, 0.f};

  const ushort* Ab = A + (size_t)tileM * D_;
  const ushort* Bb = W3T + (size_t)z * D_ * D_ + (size_t)tileN * D_;
  gemm_mainloop(Ab, Bb, As, Bs, t, wm, wn, l15, quad, acc);

  const float* gg = (z == 0) ? gq : (z == 1) ? gk : gv;
  const float* bb = (z == 0) ? bq : (z == 1) ? bk : bv;
  const float* mmn = (z == 0) ? mq : (z == 1) ? mk : mv;
  const float* vvn = (z == 0) ? vq : (z == 1) ? vk : vv;

  if (z == 2) {
#pragma unroll
    for (int tn = 0; tn < 4; tn++) {
      int col = tileN + wn * 64 + tn * 16 + l15;
      float sc = gg[col] * rsqrtf(vvn[col] + 1e-5f);
      float sh = bb[col] - mmn[col] * sc;
#pragma unroll
      for (int tm = 0; tm < 4; tm++) {
        int row0 = tileM + wm * 64 + tm * 16 + quad * 4;
#pragma unroll
        for (int r = 0; r < 4; r++)
          Vb[(size_t)(row0 + r) * D_ + col] = f2bf(sig4(acc[tm][tn][r] * sc + sh));
      }
    }
  } else {
    float* rowsum = (z == 0) ? rsQ : rsK;
    float rs[4][4];
#pragma unroll
    for (int tm = 0; tm < 4; tm++)
#pragma unroll
      for (int r = 0; r < 4; r++) rs[tm][r] = 0.f;
#pragma unroll
    for (int tn = 0; tn < 4; tn++) {
      int col = tileN + wn * 64 + tn * 16 + l15;
      float sc = gg[col] * rsqrtf(vvn[col] + 1e-5f);
      float sh = bb[col] - mmn[col] * sc;
#pragma unroll
      for (int tm = 0; tm < 4; tm++)
#pragma unroll
        for (int r = 0; r < 4; r++)
          rs[tm][r] += sig4(acc[tm][tn][r] * sc + sh);
    }
#pragma unroll
    for (int off = 1; off < 16; off <<= 1)
#pragma unroll
      for (int tm = 0; tm < 4; tm++)
#pragma unroll
        for (int r = 0; r < 4; r++)
          rs[tm][r] += __shfl_xor(rs[tm][r], off, 64);
    if (l15 == 0) {
#pragma unroll
      for (int tm = 0; tm < 4; tm++) {
        int row0 = tileM + wm * 64 + tm * 16 + quad * 4;
#pragma unroll
        for (int r = 0; r < 4; r++)
          atomicAdd(&rowsum[row0 + r], rs[tm][r]);
      }
    }
  }
}

// ---------------- final GEMM: AVb @ WoT^T + bo -> fp32 out ----------------
__global__ __launch_bounds__(256) void gemm_out_k(
    const ushort* __restrict__ A, const ushort* __restrict__ Bt,
    float* __restrict__ outF, const float* __restrict__ bo)
{
  __shared__ ushort As[128 * 32];
  __shared__ ushort Bs[128 * 32];
  const int t = threadIdx.x;
  const int lane = t & 63, wid = t >> 6;
  const int quad = lane >> 4, l15 = lane & 15;
  const int wm = wid >> 1, wn = wid & 1;
  const int tileM = blockIdx.y * 128, tileN = blockIdx.x * 128;

  floatx4 acc[4][4];
#pragma unroll
  for (int i = 0; i < 4; i++)
#pragma unroll
    for (int j = 0; j < 4; j++) acc[i][j] = (floatx4){0.f, 0.f, 0.f, 0.f};

  const ushort* Ab = A + (size_t)tileM * D_;
  const ushort* Bb = Bt + (size_t)tileN * D_;
  gemm_mainloop(Ab, Bb, As, Bs, t, wm, wn, l15, quad, acc);

#pragma unroll
  for (int tn = 0; tn < 4; tn++) {
    int col = tileN + wn * 64 + tn * 16 + l15;
    float bias = bo[col];
#pragma unroll
    for (int tm = 0; tm < 4; tm++) {
      int row0 = tileM + wm * 64 + tm * 16 + quad * 4;
#pragma unroll
      for (int r = 0; r < 4; r++)
        outF[(size_t)(row0 + r) * D_ + col] = acc[tm][tn][r] + bias;
    }
  }
}

// ---------------- rank-by-counting event sort ----------------
// Positive floats: IEEE bits are order-monotone. key = (f32bits<<32)|(isq<<16)|idx.
// Keys (isq=0) sort before queries (isq=1) on value ties == reference's dt<0 branch.
__global__ __launch_bounds__(256) void rank_events_k(
    const float* __restrict__ rsQ, const float* __restrict__ rsK,
    int* __restrict__ evt_tag, float* __restrict__ evt_wa, float* __restrict__ evt_wd)
{
  __shared__ unsigned long long keys[4096];  // 32 KB
  __shared__ int part[256];
  int b = blockIdx.y, chunk = blockIdx.x;    // chunk 0..31 of 128 events
  int t = threadIdx.x;
  for (int i = t; i < 4096; i += 256) {
    float v; unsigned tag;
    if (i < 2048) {
      v = 1.0f - rsQ[b * N_ + i] * (1.0f / 1024.0f);
      tag = (unsigned)i | 0x10000u;          // query
    } else {
      int j = i - 2048;
      v = 1.0f - rsK[b * N_ + j] * (1.0f / 1024.0f);
      tag = (unsigned)j;                     // key
    }
    keys[i] = ((unsigned long long)__builtin_bit_cast(unsigned, v) << 32) | tag;
  }
  __syncthreads();
  // 2 threads per event, each counts one half of the 4096 comparisons
  int e = chunk * 128 + (t & 127);
  int j0 = (t >> 7) * 2048;
  unsigned long long me = keys[e];
  int r = 0;
#pragma unroll 8
  for (int j = 0; j < 2048; j++) r += (keys[j0 + j] < me) ? 1 : 0;
  part[t] = r;
  __syncthreads();
  if (t < 128) {
    int rank = part[t] + part[t + 128];      // unique: keys are distinct (idx in low bits)
    unsigned tag = (unsigned)(me & 0x1FFFFu);
    float v = __builtin_bit_cast(float, (unsigned)(me >> 32));
    bool isq = (tag & 0x10000u) != 0;
    int o = b * 4096 + rank;
    evt_tag[o] = (int)tag;
    // keys: wa=e^{2tk}, wd=e^{-2tk};  queries: wa=e^{-2tq}, wd=e^{2tq}
    evt_wa[o] = isq ? expf(-2.0f * v) : expf(2.0f * v);
    evt_wd[o] = isq ? expf(2.0f * v) : expf(-2.0f * v);
  }
}

// ---------------- segment totals ----------------
__global__ __launch_bounds__(256) void seg_tot_k(
    const int* __restrict__ evt_tag, const float* __restrict__ evt_wa,
    const float* __restrict__ evt_wd, const ushort* __restrict__ Vb,
    float* __restrict__ totWA, float* __restrict__ totWD, float* __restrict__ totP)
{
  int b = blockIdx.z, seg = blockIdx.y, chunk = blockIdx.x;
  int t = threadIdx.x;
  int c = chunk * 512 + t * 2;
  float wa0 = 0, wa1 = 0, wd0 = 0, wd1 = 0, p0 = 0, p1 = 0;
  int e0 = b * 4096 + seg * EPB;
  for (int e = 0; e < EPB; e++) {
    int tg = evt_tag[e0 + e];
    if (tg & 0x10000) continue;  // query
    int j = tg & 0xFFFF;
    unsigned raw = *(const unsigned*)(Vb + ((size_t)b * N_ + j) * D_ + c);
    float v0 = bf2f((ushort)(raw & 0xffffu)), v1 = bf2f((ushort)(raw >> 16));
    float wa = evt_wa[e0 + e], wd = evt_wd[e0 + e];
    wa0 += wa * v0; wa1 += wa * v1;
    wd0 += wd * v0; wd1 += wd * v1;
    p0 += v0; p1 += v1;
  }
  size_t o = ((size_t)b * SEGS + seg) * D_ + c;
  totWA[o] = wa0; totWA[o + 1] = wa1;
  totWD[o] = wd0; totWD[o + 1] = wd1;
  totP[o]  = p0;  totP[o + 1]  = p1;
}

// ---------------- fused asc+desc scan ----------------
// Asc pass writes per-query partial to AVpart (global); desc pass re-reads the
// SAME thread's writes (program-order coherent) and finalizes to bf16 AVb.
__global__ __launch_bounds__(256) void scan_both_k(
    const int* __restrict__ evt_tag, const float* __restrict__ evt_wa,
    const float* __restrict__ evt_wd, const ushort* __restrict__ Vb,
    const float* __restrict__ totWA, const float* __restrict__ totWD,
    const float* __restrict__ totP, float* AVpart, ushort* __restrict__ AVb)
{
  int b = blockIdx.z, seg = blockIdx.y, chunk = blockIdx.x;
  int t = threadIdx.x;
  int c = chunk * 512 + t * 2;
  int e0 = b * 4096 + seg * EPB;

  // ---- ascending: low-side (tk <= tq): 0.9*(Plow - e^{-2tq} * sum e^{2tk} V)
  {
    float s0 = 0, s1 = 0, p0 = 0, p1 = 0;
    for (int s = 0; s < seg; s++) {
      size_t o = ((size_t)b * SEGS + s) * D_ + c;
      s0 += totWA[o]; s1 += totWA[o + 1];
      p0 += totP[o];  p1 += totP[o + 1];
    }
    for (int e = 0; e < EPB; e++) {
      int tg = evt_tag[e0 + e];
      float w = evt_wa[e0 + e];
      int idx = tg & 0xFFFF;
      if (tg & 0x10000) {
        size_t o = ((size_t)b * N_ + idx) * D_ + c;
        AVpart[o]     = 0.9f * (p0 - w * s0);
        AVpart[o + 1] = 0.9f * (p1 - w * s1);
      } else {
        unsigned raw = *(const unsigned*)(Vb + ((size_t)b * N_ + idx) * D_ + c);
        float v0 = bf2f((ushort)(raw & 0xffffu)), v1 = bf2f((ushort)(raw >> 16));
        s0 += w * v0; s1 += w * v1;
        p0 += v0;     p1 += v1;
      }
    }
  }
  // ---- descending: high-side (tk > tq): 0.9*(Phigh + e^{2tq} * sum e^{-2tk} V)
  {
    float s0 = 0, s1 = 0, p0 = 0, p1 = 0;
    for (int s = seg + 1; s < SEGS; s++) {
      size_t o = ((size_t)b * SEGS + s) * D_ + c;
      s0 += totWD[o]; s1 += totWD[o + 1];
      p0 += totP[o];  p1 += totP[o + 1];
    }
    for (int e = EPB - 1; e >= 0; e--) {
      int tg = evt_tag[e0 + e];
      float w = evt_wd[e0 + e];
      int idx = tg & 0xFFFF;
      if (tg & 0x10000) {
        size_t o = ((size_t)b * N_ + idx) * D_ + c;
        float r0 = AVpart[o]     + 0.9f * (p0 + w * s0);
        float r1 = AVpart[o + 1] + 0.9f * (p1 + w * s1);
        AVb[o] = f2bf(r0); AVb[o + 1] = f2bf(r1);
      } else {
        unsigned raw = *(const unsigned*)(Vb + ((size_t)b * N_ + idx) * D_ + c);
        float v0 = bf2f((ushort)(raw & 0xffffu)), v1 = bf2f((ushort)(raw >> 16));
        s0 += w * v0; s1 += w * v1;
        p0 += v0;     p1 += v1;
      }
    }
  }
}

extern "C" void kernel_launch(void* const* d_in, const int* in_sizes, int n_in,
                              void* d_out, int out_size, void* d_ws, size_t ws_size,
                              hipStream_t stream) {
  (void)in_sizes; (void)n_in; (void)out_size; (void)ws_size;
  const float* x  = (const float*)d_in[0];
  const float* Wq = (const float*)d_in[1];
  const float* gq = (const float*)d_in[2];
  const float* bq = (const float*)d_in[3];
  const float* mq = (const float*)d_in[4];
  const float* vq = (const float*)d_in[5];
  const float* Wk = (const float*)d_in[6];
  const float* gk = (const float*)d_in[7];
  const float* bk = (const float*)d_in[8];
  const float* mk = (const float*)d_in[9];
  const float* vk = (const float*)d_in[10];
  const float* Wv = (const float*)d_in[11];
  const float* gv = (const float*)d_in[12];
  const float* bv = (const float*)d_in[13];
  const float* mv = (const float*)d_in[14];
  const float* vv = (const float*)d_in[15];
  const float* Wo = (const float*)d_in[16];
  const float* bo = (const float*)d_in[17];

  char* p = (char*)d_ws;
  auto alloc = [&](size_t n) { char* r = p; p += n; return r; };
  ushort* x16  = (ushort*)alloc((size_t)M_ * D_ * 2);
  ushort* Vb   = (ushort*)alloc((size_t)M_ * D_ * 2);
  ushort* AVb  = (ushort*)alloc((size_t)M_ * D_ * 2);
  ushort* W3T  = (ushort*)alloc((size_t)3 * D_ * D_ * 2);
  ushort* WoT  = (ushort*)alloc((size_t)D_ * D_ * 2);
  float*  rsQ  = (float*)alloc((size_t)M_ * 4);
  float*  rsK  = (float*)alloc((size_t)M_ * 4);
  int*    evt_tag = (int*)alloc((size_t)B_ * 4096 * 4);
  float*  evt_wa  = (float*)alloc((size_t)B_ * 4096 * 4);
  float*  evt_wd  = (float*)alloc((size_t)B_ * 4096 * 4);
  float*  totWA   = (float*)alloc((size_t)B_ * SEGS * D_ * 4);
  float*  totWD   = (float*)alloc((size_t)B_ * SEGS * D_ * 4);
  float*  totP    = (float*)alloc((size_t)B_ * SEGS * D_ * 4);

  // zero the row-sum accumulators (rsQ, rsK are adjacent)
  hipMemsetAsync(rsQ, 0, (size_t)2 * M_ * 4, stream);

  conv_x_k<<<(M_ * D_) / 1024, 256, 0, stream>>>((const float4*)x, (ushort4*)x16);
  dim3 tb(32, 8), tg(32, 32, 4);
  transpose_k<<<tg, tb, 0, stream>>>(Wq, Wk, Wv, Wo, W3T, WoT);

  dim3 gqkv(D_ / 128, M_ / 128, 3);
  gemm_qkv_k<<<gqkv, 256, 0, stream>>>(x16, W3T, gq, bq, mq, vq,
                                       gk, bk, mk, vk, gv, bv, mv, vv,
                                       rsQ, rsK, Vb);

  rank_events_k<<<dim3(32, B_), 256, 0, stream>>>(rsQ, rsK, evt_tag, evt_wa, evt_wd);

  dim3 sg(2, SEGS, B_);
  seg_tot_k<<<sg, 256, 0, stream>>>(evt_tag, evt_wa, evt_wd, Vb, totWA, totWD, totP);
  scan_both_k<<<sg, 256, 0, stream>>>(evt_tag, evt_wa, evt_wd, Vb, totWA, totWD, totP,
                                      (float*)d_out, AVb);

  dim3 gg(D_ / 128, M_ / 128);
  gemm_out_k<<<gg, 256, 0, stream>>>(AVb, WoT, (float*)d_out, bo);
}

// Round 3
// 512.202 us; speedup vs baseline: 1.1428x; 1.0296x over previous
//
#include <hip/hip_runtime.h>

#define B_ 8
#define N_ 2048
#define D_ 1024
#define M_ (B_*N_)          // 16384 rows
#define SEGS 32
#define EPB (4096/SEGS)     // 128 events per segment
#define CW 256              // scan chunk width (cols per block)

typedef __attribute__((ext_vector_type(8))) short short8;
typedef __attribute__((ext_vector_type(4))) float floatx4;

__device__ __forceinline__ ushort f2bf(float f) {
  unsigned u = __builtin_bit_cast(unsigned, f);
  return (ushort)((u + 0x7fffu + ((u >> 16) & 1u)) >> 16);
}
__device__ __forceinline__ float bf2f(ushort u) {
  return __builtin_bit_cast(float, ((unsigned)u) << 16);
}
__device__ __forceinline__ void gload16(const void* g, void* l) {
  __builtin_amdgcn_global_load_lds(
      (const __attribute__((address_space(1))) unsigned*)g,
      (__attribute__((address_space(3))) unsigned*)l, 16, 0, 0);
}
__device__ __forceinline__ float sig4(float h) {
  // sigmoid(4*(h-1))
  return 1.0f / (1.0f + __expf(4.0f - 4.0f*h));
}

// ---------------- conversions ----------------
__global__ __launch_bounds__(256) void conv_x_k(const float4* __restrict__ x,
                                                ushort4* __restrict__ o) {
  int i = blockIdx.x * 256 + threadIdx.x;
  float4 f = x[i];
  ushort4 u;
  u.x = f2bf(f.x); u.y = f2bf(f.y); u.z = f2bf(f.z); u.w = f2bf(f.w);
  o[i] = u;
}

// all 4 weight transposes in one launch; z selects the matrix
__global__ __launch_bounds__(256) void transpose_k(
    const float* __restrict__ Wq, const float* __restrict__ Wk,
    const float* __restrict__ Wv, const float* __restrict__ Wo,
    ushort* __restrict__ W3T, ushort* __restrict__ WoT) {
  __shared__ float tile[32][33];
  int z = blockIdx.z;
  const float* W = (z == 0) ? Wq : (z == 1) ? Wk : (z == 2) ? Wv : Wo;
  ushort* WT = (z < 3) ? (W3T + (size_t)z * D_ * D_) : WoT;
  int tx = threadIdx.x, ty = threadIdx.y;
  int x = blockIdx.x * 32 + tx;
  int y = blockIdx.y * 32 + ty;
#pragma unroll
  for (int j = 0; j < 32; j += 8)
    tile[ty + j][tx] = W[(size_t)(y + j) * D_ + x];
  __syncthreads();
  int x2 = blockIdx.y * 32 + tx;
  int y2 = blockIdx.x * 32 + ty;
#pragma unroll
  for (int j = 0; j < 32; j += 8)
    WT[(size_t)(y2 + j) * D_ + x2] = f2bf(tile[tx][ty + j]);
}

// ---------------- GEMM mainloop: 128x128 tile, BK=64, swizzled LDS ----------
// LDS layout: row stride 128B (64 ushorts). Physical 16B-chunk c of row r holds
// logical chunk (c - r) & 7  -> fragment reads are bank-conflict-free, and the
// global_load_lds per-row chunk rotation is free (same address union per wave).
__device__ __forceinline__ void gemm_mainloop(
    const ushort* __restrict__ Ab, const ushort* __restrict__ Bb,
    ushort* As, ushort* Bs, int t, int wm, int wn, int l15, int quad,
    floatx4 acc[4][4])
{
  int srow[4], soff[4];
#pragma unroll
  for (int r = 0; r < 4; r++) {
    int li = r * 256 + t;
    int row = li >> 3, c = li & 7;
    srow[r] = row;
    soff[r] = ((c - row) & 7) * 8;   // logical chunk held by physical chunk c
  }
  for (int k0 = 0; k0 < D_; k0 += 64) {
    __syncthreads();
#pragma unroll
    for (int r = 0; r < 4; r++) {
      int li = r * 256 + t;
      gload16(Ab + (size_t)srow[r] * D_ + k0 + soff[r], (char*)As + li * 16);
      gload16(Bb + (size_t)srow[r] * D_ + k0 + soff[r], (char*)Bs + li * 16);
    }
    __syncthreads();
#pragma unroll
    for (int s = 0; s < 2; s++) {
      short8 af[4], bfr[4];
#pragma unroll
      for (int tm = 0; tm < 4; tm++) {
        int row = wm * 64 + tm * 16 + l15;
        int p = (s * 4 + quad + row) & 7;
        af[tm] = *(const short8*)(As + row * 64 + p * 8);
      }
#pragma unroll
      for (int tn = 0; tn < 4; tn++) {
        int row = wn * 64 + tn * 16 + l15;
        int p = (s * 4 + quad + row) & 7;
        bfr[tn] = *(const short8*)(Bs + row * 64 + p * 8);
      }
#pragma unroll
      for (int tm = 0; tm < 4; tm++)
#pragma unroll
        for (int tn = 0; tn < 4; tn++)
          acc[tm][tn] = __builtin_amdgcn_mfma_f32_16x16x32_bf16(af[tm], bfr[tn], acc[tm][tn], 0, 0, 0);
    }
  }
}

// ---------------- fused QKV GEMM: z=0 Q-rowsum, z=1 K-rowsum, z=2 V-store ----
__global__ __launch_bounds__(256) void gemm_qkv_k(
    const ushort* __restrict__ A, const ushort* __restrict__ W3T,
    const float* __restrict__ gq, const float* __restrict__ bq,
    const float* __restrict__ mq, const float* __restrict__ vq,
    const float* __restrict__ gk, const float* __restrict__ bk,
    const float* __restrict__ mk, const float* __restrict__ vk,
    const float* __restrict__ gv, const float* __restrict__ bv,
    const float* __restrict__ mv, const float* __restrict__ vv,
    float* __restrict__ rsQ, float* __restrict__ rsK, ushort* __restrict__ Vb)
{
  __shared__ ushort As[128 * 64];
  __shared__ ushort Bs[128 * 64];
  const int t = threadIdx.x;
  const int lane = t & 63, wid = t >> 6;
  const int quad = lane >> 4, l15 = lane & 15;
  const int wm = wid >> 1, wn = wid & 1;
  const int tileM = blockIdx.y * 128, tileN = blockIdx.x * 128;
  const int z = blockIdx.z;

  floatx4 acc[4][4];
#pragma unroll
  for (int i = 0; i < 4; i++)
#pragma unroll
    for (int j = 0; j < 4; j++) acc[i][j] = (floatx4){0.f, 0.f, 0.f, 0.f};

  const ushort* Ab = A + (size_t)tileM * D_;
  const ushort* Bb = W3T + (size_t)z * D_ * D_ + (size_t)tileN * D_;
  gemm_mainloop(Ab, Bb, As, Bs, t, wm, wn, l15, quad, acc);

  const float* gg = (z == 0) ? gq : (z == 1) ? gk : gv;
  const float* bb = (z == 0) ? bq : (z == 1) ? bk : bv;
  const float* mmn = (z == 0) ? mq : (z == 1) ? mk : mv;
  const float* vvn = (z == 0) ? vq : (z == 1) ? vk : vv;

  if (z == 2) {
#pragma unroll
    for (int tn = 0; tn < 4; tn++) {
      int col = tileN + wn * 64 + tn * 16 + l15;
      float sc = gg[col] * rsqrtf(vvn[col] + 1e-5f);
      float sh = bb[col] - mmn[col] * sc;
#pragma unroll
      for (int tm = 0; tm < 4; tm++) {
        int row0 = tileM + wm * 64 + tm * 16 + quad * 4;
#pragma unroll
        for (int r = 0; r < 4; r++)
          Vb[(size_t)(row0 + r) * D_ + col] = f2bf(sig4(acc[tm][tn][r] * sc + sh));
      }
    }
  } else {
    float* rowsum = (z == 0) ? rsQ : rsK;
    float rs[4][4];
#pragma unroll
    for (int tm = 0; tm < 4; tm++)
#pragma unroll
      for (int r = 0; r < 4; r++) rs[tm][r] = 0.f;
#pragma unroll
    for (int tn = 0; tn < 4; tn++) {
      int col = tileN + wn * 64 + tn * 16 + l15;
      float sc = gg[col] * rsqrtf(vvn[col] + 1e-5f);
      float sh = bb[col] - mmn[col] * sc;
#pragma unroll
      for (int tm = 0; tm < 4; tm++)
#pragma unroll
        for (int r = 0; r < 4; r++)
          rs[tm][r] += sig4(acc[tm][tn][r] * sc + sh);
    }
#pragma unroll
    for (int off = 1; off < 16; off <<= 1)
#pragma unroll
      for (int tm = 0; tm < 4; tm++)
#pragma unroll
        for (int r = 0; r < 4; r++)
          rs[tm][r] += __shfl_xor(rs[tm][r], off, 64);
    if (l15 == 0) {
#pragma unroll
      for (int tm = 0; tm < 4; tm++) {
        int row0 = tileM + wm * 64 + tm * 16 + quad * 4;
#pragma unroll
        for (int r = 0; r < 4; r++)
          atomicAdd(&rowsum[row0 + r], rs[tm][r]);
      }
    }
  }
}

// ---------------- final GEMM: AVb @ WoT^T + bo -> fp32 out ----------------
__global__ __launch_bounds__(256) void gemm_out_k(
    const ushort* __restrict__ A, const ushort* __restrict__ Bt,
    float* __restrict__ outF, const float* __restrict__ bo)
{
  __shared__ ushort As[128 * 64];
  __shared__ ushort Bs[128 * 64];
  const int t = threadIdx.x;
  const int lane = t & 63, wid = t >> 6;
  const int quad = lane >> 4, l15 = lane & 15;
  const int wm = wid >> 1, wn = wid & 1;
  const int tileM = blockIdx.y * 128, tileN = blockIdx.x * 128;

  floatx4 acc[4][4];
#pragma unroll
  for (int i = 0; i < 4; i++)
#pragma unroll
    for (int j = 0; j < 4; j++) acc[i][j] = (floatx4){0.f, 0.f, 0.f, 0.f};

  const ushort* Ab = A + (size_t)tileM * D_;
  const ushort* Bb = Bt + (size_t)tileN * D_;
  gemm_mainloop(Ab, Bb, As, Bs, t, wm, wn, l15, quad, acc);

#pragma unroll
  for (int tn = 0; tn < 4; tn++) {
    int col = tileN + wn * 64 + tn * 16 + l15;
    float bias = bo[col];
#pragma unroll
    for (int tm = 0; tm < 4; tm++) {
      int row0 = tileM + wm * 64 + tm * 16 + quad * 4;
#pragma unroll
      for (int r = 0; r < 4; r++)
        outF[(size_t)(row0 + r) * D_ + col] = acc[tm][tn][r] + bias;
    }
  }
}

// ---------------- rank-by-counting event sort ----------------
__global__ __launch_bounds__(256) void rank_events_k(
    const float* __restrict__ rsQ, const float* __restrict__ rsK,
    int* __restrict__ evt_tag, float* __restrict__ evt_wa, float* __restrict__ evt_wd)
{
  __shared__ unsigned long long keys[4096];  // 32 KB
  __shared__ int part[256];
  int b = blockIdx.y, chunk = blockIdx.x;    // chunk 0..31 of 128 events
  int t = threadIdx.x;
  for (int i = t; i < 4096; i += 256) {
    float v; unsigned tag;
    if (i < 2048) {
      v = 1.0f - rsQ[b * N_ + i] * (1.0f / 1024.0f);
      tag = (unsigned)i | 0x10000u;          // query
    } else {
      int j = i - 2048;
      v = 1.0f - rsK[b * N_ + j] * (1.0f / 1024.0f);
      tag = (unsigned)j;                     // key
    }
    keys[i] = ((unsigned long long)__builtin_bit_cast(unsigned, v) << 32) | tag;
  }
  __syncthreads();
  int e = chunk * 128 + (t & 127);
  int j0 = (t >> 7) * 2048;
  unsigned long long me = keys[e];
  int r = 0;
#pragma unroll 8
  for (int j = 0; j < 2048; j++) r += (keys[j0 + j] < me) ? 1 : 0;
  part[t] = r;
  __syncthreads();
  if (t < 128) {
    int rank = part[t] + part[t + 128];
    unsigned tag = (unsigned)(me & 0x1FFFFu);
    float v = __builtin_bit_cast(float, (unsigned)(me >> 32));
    bool isq = (tag & 0x10000u) != 0;
    int o = b * 4096 + rank;
    evt_tag[o] = (int)tag;
    // keys: wa=e^{2tk}, wd=e^{-2tk};  queries: wa=e^{-2tq}, wd=e^{2tq}
    evt_wa[o] = isq ? expf(-2.0f * v) : expf(2.0f * v);
    evt_wd[o] = isq ? expf(2.0f * v) : expf(-2.0f * v);
  }
}

// ---------------- segment totals (branch-free, pipelined) ----------------
__global__ __launch_bounds__(256) void seg_tot_k(
    const int* __restrict__ evt_tag, const float* __restrict__ evt_wa,
    const float* __restrict__ evt_wd, const ushort* __restrict__ Vb,
    float* __restrict__ totWA, float* __restrict__ totWD, float* __restrict__ totP)
{
  __shared__ int srow[EPB];
  __shared__ float swa[EPB], swd[EPB], spw[EPB];
  int b = blockIdx.z, seg = blockIdx.y, chunk = blockIdx.x;
  int t = threadIdx.x;
  int e0 = b * 4096 + seg * EPB;
  if (t < EPB) {
    int tg = evt_tag[e0 + t];
    bool isk = !(tg & 0x10000);
    srow[t] = isk ? (tg & 0xFFFF) : 0;   // queries read (hot) row 0, weight 0
    swa[t] = isk ? evt_wa[e0 + t] : 0.f;
    swd[t] = isk ? evt_wd[e0 + t] : 0.f;
    spw[t] = isk ? 1.f : 0.f;
  }
  __syncthreads();
  int c = chunk * 512 + t * 2;
  const ushort* vb = Vb + (size_t)b * N_ * D_ + c;
  float wa0 = 0, wa1 = 0, wd0 = 0, wd1 = 0, p0 = 0, p1 = 0;
#pragma unroll 8
  for (int e = 0; e < EPB; e++) {
    unsigned raw = *(const unsigned*)(vb + (size_t)srow[e] * D_);
    float v0 = bf2f((ushort)(raw & 0xffffu)), v1 = bf2f((ushort)(raw >> 16));
    float wa = swa[e], wd = swd[e], pw = spw[e];
    wa0 += wa * v0; wa1 += wa * v1;
    wd0 += wd * v0; wd1 += wd * v1;
    p0 += pw * v0;  p1 += pw * v1;
  }
  size_t o = ((size_t)b * SEGS + seg) * D_ + c;
  totWA[o] = wa0; totWA[o + 1] = wa1;
  totWD[o] = wd0; totWD[o + 1] = wd1;
  totP[o]  = p0;  totP[o + 1]  = p1;
}

// ---------------- fused asc+desc scan with LDS-staged V tile ----------------
__global__ __launch_bounds__(256) void scan_both_k(
    const int* __restrict__ evt_tag, const float* __restrict__ evt_wa,
    const float* __restrict__ evt_wd, const ushort* __restrict__ Vb,
    const float* __restrict__ totWA, const float* __restrict__ totWD,
    const float* __restrict__ totP, float* AVpart, ushort* __restrict__ AVb)
{
  __shared__ ushort Vt[EPB * CW];        // 64 KB: event-major V tile
  __shared__ int stag[EPB], srow[EPB];
  __shared__ float swa[EPB], swd[EPB];
  int b = blockIdx.z, seg = blockIdx.y, chunk = blockIdx.x;
  int t = threadIdx.x;
  int e0 = b * 4096 + seg * EPB;
  if (t < EPB) {
    int tg = evt_tag[e0 + t];
    stag[t] = tg;
    srow[t] = (tg & 0x10000) ? 0 : (tg & 0xFFFF);
    swa[t] = evt_wa[e0 + t];
    swd[t] = evt_wd[e0 + t];
  }
  __syncthreads();
  int c0 = chunk * CW;
  const ushort* vbase = Vb + (size_t)b * N_ * D_ + c0;
  // stage 128 events x 256 cols (512B/row = 32 x16B chunks) via global_load_lds
#pragma unroll
  for (int r = 0; r < 16; r++) {
    int li = r * 256 + t;
    int e = li >> 5, ch = li & 31;
    gload16(vbase + (size_t)srow[e] * D_ + ch * 8, (char*)Vt + li * 16);
  }
  __syncthreads();

  int cth = c0 + t;  // this thread's column
  // cross-segment prefixes
  float sA = 0, pA = 0, sD = 0, pD = 0;
  for (int s = 0; s < seg; s++) {
    size_t o = ((size_t)b * SEGS + s) * D_ + cth;
    sA += totWA[o]; pA += totP[o];
  }
  for (int s = seg + 1; s < SEGS; s++) {
    size_t o = ((size_t)b * SEGS + s) * D_ + cth;
    sD += totWD[o]; pD += totP[o];
  }
  float* AVrow = AVpart + (size_t)b * N_ * D_ + cth;
  ushort* AVbrow = AVb + (size_t)b * N_ * D_ + cth;

  // ascending: low side (tk <= tq): 0.9*(Plow - e^{-2tq} * sum e^{2tk} V)
  {
    float s = sA, p = pA;
    for (int e = 0; e < EPB; e++) {
      int tg = stag[e];
      float w = swa[e];
      if (tg & 0x10000) {
        AVrow[(size_t)(tg & 0xFFFF) * D_] = 0.9f * (p - w * s);
      } else {
        float v = bf2f(Vt[e * CW + t]);
        s += w * v; p += v;
      }
    }
  }
  // descending: high side (tk > tq): 0.9*(Phigh + e^{2tq} * sum e^{-2tk} V)
  {
    float s = sD, p = pD;
    for (int e = EPB - 1; e >= 0; e--) {
      int tg = stag[e];
      float w = swd[e];
      if (tg & 0x10000) {
        size_t o = (size_t)(tg & 0xFFFF) * D_;
        float rr = AVrow[o] + 0.9f * (p + w * s);
        AVbrow[o] = f2bf(rr);
      } else {
        float v = bf2f(Vt[e * CW + t]);
        s += w * v; p += v;
      }
    }
  }
}

extern "C" void kernel_launch(void* const* d_in, const int* in_sizes, int n_in,
                              void* d_out, int out_size, void* d_ws, size_t ws_size,
                              hipStream_t stream) {
  (void)in_sizes; (void)n_in; (void)out_size; (void)ws_size;
  const float* x  = (const float*)d_in[0];
  const float* Wq = (const float*)d_in[1];
  const float* gq = (const float*)d_in[2];
  const float* bq = (const float*)d_in[3];
  const float* mq = (const float*)d_in[4];
  const float* vq = (const float*)d_in[5];
  const float* Wk = (const float*)d_in[6];
  const float* gk = (const float*)d_in[7];
  const float* bk = (const float*)d_in[8];
  const float* mk = (const float*)d_in[9];
  const float* vk = (const float*)d_in[10];
  const float* Wv = (const float*)d_in[11];
  const float* gv = (const float*)d_in[12];
  const float* bv = (const float*)d_in[13];
  const float* mv = (const float*)d_in[14];
  const float* vv = (const float*)d_in[15];
  const float* Wo = (const float*)d_in[16];
  const float* bo = (const float*)d_in[17];

  char* p = (char*)d_ws;
  auto alloc = [&](size_t n) { char* r = p; p += n; return r; };
  ushort* x16  = (ushort*)alloc((size_t)M_ * D_ * 2);
  ushort* Vb   = (ushort*)alloc((size_t)M_ * D_ * 2);
  ushort* AVb  = (ushort*)alloc((size_t)M_ * D_ * 2);
  ushort* W3T  = (ushort*)alloc((size_t)3 * D_ * D_ * 2);
  ushort* WoT  = (ushort*)alloc((size_t)D_ * D_ * 2);
  float*  rsQ  = (float*)alloc((size_t)M_ * 4);
  float*  rsK  = (float*)alloc((size_t)M_ * 4);
  int*    evt_tag = (int*)alloc((size_t)B_ * 4096 * 4);
  float*  evt_wa  = (float*)alloc((size_t)B_ * 4096 * 4);
  float*  evt_wd  = (float*)alloc((size_t)B_ * 4096 * 4);
  float*  totWA   = (float*)alloc((size_t)B_ * SEGS * D_ * 4);
  float*  totWD   = (float*)alloc((size_t)B_ * SEGS * D_ * 4);
  float*  totP    = (float*)alloc((size_t)B_ * SEGS * D_ * 4);

  hipMemsetAsync(rsQ, 0, (size_t)2 * M_ * 4, stream);

  conv_x_k<<<(M_ * D_) / 1024, 256, 0, stream>>>((const float4*)x, (ushort4*)x16);
  dim3 tb(32, 8), tg(32, 32, 4);
  transpose_k<<<tg, tb, 0, stream>>>(Wq, Wk, Wv, Wo, W3T, WoT);

  dim3 gqkv(D_ / 128, M_ / 128, 3);
  gemm_qkv_k<<<gqkv, 256, 0, stream>>>(x16, W3T, gq, bq, mq, vq,
                                       gk, bk, mk, vk, gv, bv, mv, vv,
                                       rsQ, rsK, Vb);

  rank_events_k<<<dim3(32, B_), 256, 0, stream>>>(rsQ, rsK, evt_tag, evt_wa, evt_wd);

  seg_tot_k<<<dim3(2, SEGS, B_), 256, 0, stream>>>(evt_tag, evt_wa, evt_wd, Vb,
                                                   totWA, totWD, totP);
  scan_both_k<<<dim3(D_ / CW, SEGS, B_), 256, 0, stream>>>(
      evt_tag, evt_wa, evt_wd, Vb, totWA, totWD, totP, (float*)d_out, AVb);

  dim3 gg(D_ / 128, M_ / 128);
  gemm_out_k<<<gg, 256, 0, stream>>>(AVb, WoT, (float*)d_out, bo);
}

// Round 4
// 468.014 us; speedup vs baseline: 1.2507x; 1.0944x over previous
//
#include <hip/hip_runtime.h>

#define B_ 8
#define N_ 2048
#define D_ 1024
#define M_ (B_*N_)          // 16384 rows
#define SEGS 64
#define EPB (4096/SEGS)     // 64 events per segment
#define CW 256              // scan chunk width (cols per block)

typedef __attribute__((ext_vector_type(8))) short short8;
typedef __attribute__((ext_vector_type(4))) float floatx4;

__device__ __forceinline__ ushort f2bf(float f) {
  unsigned u = __builtin_bit_cast(unsigned, f);
  return (ushort)((u + 0x7fffu + ((u >> 16) & 1u)) >> 16);
}
__device__ __forceinline__ float bf2f(ushort u) {
  return __builtin_bit_cast(float, ((unsigned)u) << 16);
}
__device__ __forceinline__ void gload16(const void* g, void* l) {
  __builtin_amdgcn_global_load_lds(
      (const __attribute__((address_space(1))) unsigned*)g,
      (__attribute__((address_space(3))) unsigned*)l, 16, 0, 0);
}
__device__ __forceinline__ float sig4(float h) {
  // sigmoid(4*(h-1))
  return 1.0f / (1.0f + __expf(4.0f - 4.0f*h));
}

// ---------------- conversions ----------------
__global__ __launch_bounds__(256) void conv_x_k(const float4* __restrict__ x,
                                                ushort4* __restrict__ o) {
  int i = blockIdx.x * 256 + threadIdx.x;
  float4 f = x[i];
  ushort4 u;
  u.x = f2bf(f.x); u.y = f2bf(f.y); u.z = f2bf(f.z); u.w = f2bf(f.w);
  o[i] = u;
}

// all 4 weight transposes in one launch; z selects the matrix
__global__ __launch_bounds__(256) void transpose_k(
    const float* __restrict__ Wq, const float* __restrict__ Wk,
    const float* __restrict__ Wv, const float* __restrict__ Wo,
    ushort* __restrict__ W3T, ushort* __restrict__ WoT) {
  __shared__ float tile[32][33];
  int z = blockIdx.z;
  const float* W = (z == 0) ? Wq : (z == 1) ? Wk : (z == 2) ? Wv : Wo;
  ushort* WT = (z < 3) ? (W3T + (size_t)z * D_ * D_) : WoT;
  int tx = threadIdx.x, ty = threadIdx.y;
  int x = blockIdx.x * 32 + tx;
  int y = blockIdx.y * 32 + ty;
#pragma unroll
  for (int j = 0; j < 32; j += 8)
    tile[ty + j][tx] = W[(size_t)(y + j) * D_ + x];
  __syncthreads();
  int x2 = blockIdx.y * 32 + tx;
  int y2 = blockIdx.x * 32 + ty;
#pragma unroll
  for (int j = 0; j < 32; j += 8)
    WT[(size_t)(y2 + j) * D_ + x2] = f2bf(tile[tx][ty + j]);
}

// ---------------- GEMM mainloop: 128x128 tile, BK=64, swizzled LDS ----------
// LDS row stride 128B. Physical 16B-chunk c of row r holds logical chunk
// (c - r) & 7 -> conflict-free fragment reads (verified: SQ_LDS_BANK_CONFLICT=0).
__device__ __forceinline__ void gemm_mainloop(
    const ushort* __restrict__ Ab, const ushort* __restrict__ Bb,
    ushort* As, ushort* Bs, int t, int wm, int wn, int l15, int quad,
    floatx4 acc[4][4])
{
  int srow[4], soff[4];
#pragma unroll
  for (int r = 0; r < 4; r++) {
    int li = r * 256 + t;
    int row = li >> 3, c = li & 7;
    srow[r] = row;
    soff[r] = ((c - row) & 7) * 8;
  }
  for (int k0 = 0; k0 < D_; k0 += 64) {
    __syncthreads();
#pragma unroll
    for (int r = 0; r < 4; r++) {
      int li = r * 256 + t;
      gload16(Ab + (size_t)srow[r] * D_ + k0 + soff[r], (char*)As + li * 16);
      gload16(Bb + (size_t)srow[r] * D_ + k0 + soff[r], (char*)Bs + li * 16);
    }
    __syncthreads();
#pragma unroll
    for (int s = 0; s < 2; s++) {
      short8 af[4], bfr[4];
#pragma unroll
      for (int tm = 0; tm < 4; tm++) {
        int row = wm * 64 + tm * 16 + l15;
        int p = (s * 4 + quad + row) & 7;
        af[tm] = *(const short8*)(As + row * 64 + p * 8);
      }
#pragma unroll
      for (int tn = 0; tn < 4; tn++) {
        int row = wn * 64 + tn * 16 + l15;
        int p = (s * 4 + quad + row) & 7;
        bfr[tn] = *(const short8*)(Bs + row * 64 + p * 8);
      }
#pragma unroll
      for (int tm = 0; tm < 4; tm++)
#pragma unroll
        for (int tn = 0; tn < 4; tn++)
          acc[tm][tn] = __builtin_amdgcn_mfma_f32_16x16x32_bf16(af[tm], bfr[tn], acc[tm][tn], 0, 0, 0);
    }
  }
}

// ---------------- fused QKV GEMM, XCD-aware block remap ----------------
// 1D grid of 3072. xcd = lin&7 (round-robin heuristic). Per-XCD slot order:
// any 64 consecutive slots = 8 N-tiles x 8 M-tiles -> 4 MB working set = one
// XCD L2; z is the slowest per-XCD axis. Performance heuristic only.
__global__ __launch_bounds__(256) void gemm_qkv_k(
    const ushort* __restrict__ A, const ushort* __restrict__ W3T,
    const float* __restrict__ gq, const float* __restrict__ bq,
    const float* __restrict__ mq, const float* __restrict__ vq,
    const float* __restrict__ gk, const float* __restrict__ bk,
    const float* __restrict__ mk, const float* __restrict__ vk,
    const float* __restrict__ gv, const float* __restrict__ bv,
    const float* __restrict__ mv, const float* __restrict__ vv,
    float* __restrict__ rsQ, float* __restrict__ rsK, ushort* __restrict__ Vb)
{
  __shared__ ushort As[128 * 64];
  __shared__ ushort Bs[128 * 64];
  const int t = threadIdx.x;
  const int lane = t & 63, wid = t >> 6;
  const int quad = lane >> 4, l15 = lane & 15;
  const int wm = wid >> 1, wn = wid & 1;

  const int lin = blockIdx.x;
  const int xcd = lin & 7, s = lin >> 3;   // 384 slots per XCD
  const int z   = s >> 7;                  // 0..2
  const int yg  = (s >> 6) & 1;            // 0..1
  const int yi  = (s >> 3) & 7;            // 0..7
  const int xzi = s & 7;                   // 0..7
  const int tileM = (xcd * 16 + yg * 8 + yi) * 128;
  const int tileN = xzi * 128;

  floatx4 acc[4][4];
#pragma unroll
  for (int i = 0; i < 4; i++)
#pragma unroll
    for (int j = 0; j < 4; j++) acc[i][j] = (floatx4){0.f, 0.f, 0.f, 0.f};

  const ushort* Ab = A + (size_t)tileM * D_;
  const ushort* Bb = W3T + (size_t)z * D_ * D_ + (size_t)tileN * D_;
  gemm_mainloop(Ab, Bb, As, Bs, t, wm, wn, l15, quad, acc);

  const float* gg = (z == 0) ? gq : (z == 1) ? gk : gv;
  const float* bb = (z == 0) ? bq : (z == 1) ? bk : bv;
  const float* mmn = (z == 0) ? mq : (z == 1) ? mk : mv;
  const float* vvn = (z == 0) ? vq : (z == 1) ? vk : vv;

  if (z == 2) {
#pragma unroll
    for (int tn = 0; tn < 4; tn++) {
      int col = tileN + wn * 64 + tn * 16 + l15;
      float sc = gg[col] * rsqrtf(vvn[col] + 1e-5f);
      float sh = bb[col] - mmn[col] * sc;
#pragma unroll
      for (int tm = 0; tm < 4; tm++) {
        int row0 = tileM + wm * 64 + tm * 16 + quad * 4;
#pragma unroll
        for (int r = 0; r < 4; r++)
          Vb[(size_t)(row0 + r) * D_ + col] = f2bf(sig4(acc[tm][tn][r] * sc + sh));
      }
    }
  } else {
    float* rowsum = (z == 0) ? rsQ : rsK;
    float rs[4][4];
#pragma unroll
    for (int tm = 0; tm < 4; tm++)
#pragma unroll
      for (int r = 0; r < 4; r++) rs[tm][r] = 0.f;
#pragma unroll
    for (int tn = 0; tn < 4; tn++) {
      int col = tileN + wn * 64 + tn * 16 + l15;
      float sc = gg[col] * rsqrtf(vvn[col] + 1e-5f);
      float sh = bb[col] - mmn[col] * sc;
#pragma unroll
      for (int tm = 0; tm < 4; tm++)
#pragma unroll
        for (int r = 0; r < 4; r++)
          rs[tm][r] += sig4(acc[tm][tn][r] * sc + sh);
    }
#pragma unroll
    for (int off = 1; off < 16; off <<= 1)
#pragma unroll
      for (int tm = 0; tm < 4; tm++)
#pragma unroll
        for (int r = 0; r < 4; r++)
          rs[tm][r] += __shfl_xor(rs[tm][r], off, 64);
    if (l15 == 0) {
#pragma unroll
      for (int tm = 0; tm < 4; tm++) {
        int row0 = tileM + wm * 64 + tm * 16 + quad * 4;
#pragma unroll
        for (int r = 0; r < 4; r++)
          atomicAdd(&rowsum[row0 + r], rs[tm][r]);
      }
    }
  }
}

// ---------------- final GEMM: AVb @ WoT^T + bo -> fp32, XCD-aware -----------
__global__ __launch_bounds__(256) void gemm_out_k(
    const ushort* __restrict__ A, const ushort* __restrict__ Bt,
    float* __restrict__ outF, const float* __restrict__ bo)
{
  __shared__ ushort As[128 * 64];
  __shared__ ushort Bs[128 * 64];
  const int t = threadIdx.x;
  const int lane = t & 63, wid = t >> 6;
  const int quad = lane >> 4, l15 = lane & 15;
  const int wm = wid >> 1, wn = wid & 1;

  const int lin = blockIdx.x;
  const int xcd = lin & 7, s = lin >> 3;   // 128 slots per XCD
  const int yg = s >> 6, yi = (s >> 3) & 7, xi = s & 7;
  const int tileM = (xcd * 16 + yg * 8 + yi) * 128;
  const int tileN = xi * 128;

  floatx4 acc[4][4];
#pragma unroll
  for (int i = 0; i < 4; i++)
#pragma unroll
    for (int j = 0; j < 4; j++) acc[i][j] = (floatx4){0.f, 0.f, 0.f, 0.f};

  const ushort* Ab = A + (size_t)tileM * D_;
  const ushort* Bb = Bt + (size_t)tileN * D_;
  gemm_mainloop(Ab, Bb, As, Bs, t, wm, wn, l15, quad, acc);

#pragma unroll
  for (int tn = 0; tn < 4; tn++) {
    int col = tileN + wn * 64 + tn * 16 + l15;
    float bias = bo[col];
#pragma unroll
    for (int tm = 0; tm < 4; tm++) {
      int row0 = tileM + wm * 64 + tm * 16 + quad * 4;
#pragma unroll
      for (int r = 0; r < 4; r++)
        outF[(size_t)(row0 + r) * D_ + col] = acc[tm][tn][r] + bias;
    }
  }
}

// ---------------- rank-by-counting event sort ----------------
__global__ __launch_bounds__(256) void rank_events_k(
    const float* __restrict__ rsQ, const float* __restrict__ rsK,
    int* __restrict__ evt_tag, float* __restrict__ evt_wa, float* __restrict__ evt_wd)
{
  __shared__ unsigned long long keys[4096];  // 32 KB
  __shared__ int part[256];
  int b = blockIdx.y, chunk = blockIdx.x;
  int t = threadIdx.x;
  for (int i = t; i < 4096; i += 256) {
    float v; unsigned tag;
    if (i < 2048) {
      v = 1.0f - rsQ[b * N_ + i] * (1.0f / 1024.0f);
      tag = (unsigned)i | 0x10000u;          // query
    } else {
      int j = i - 2048;
      v = 1.0f - rsK[b * N_ + j] * (1.0f / 1024.0f);
      tag = (unsigned)j;                     // key
    }
    keys[i] = ((unsigned long long)__builtin_bit_cast(unsigned, v) << 32) | tag;
  }
  __syncthreads();
  int e = chunk * 128 + (t & 127);
  int j0 = (t >> 7) * 2048;
  unsigned long long me = keys[e];
  int r = 0;
#pragma unroll 8
  for (int j = 0; j < 2048; j++) r += (keys[j0 + j] < me) ? 1 : 0;
  part[t] = r;
  __syncthreads();
  if (t < 128) {
    int rank = part[t] + part[t + 128];
    unsigned tag = (unsigned)(me & 0x1FFFFu);
    float v = __builtin_bit_cast(float, (unsigned)(me >> 32));
    bool isq = (tag & 0x10000u) != 0;
    int o = b * 4096 + rank;
    evt_tag[o] = (int)tag;
    // keys: wa=e^{2tk}, wd=e^{-2tk};  queries: wa=e^{-2tq}, wd=e^{2tq}
    evt_wa[o] = isq ? expf(-2.0f * v) : expf(2.0f * v);
    evt_wd[o] = isq ? expf(2.0f * v) : expf(-2.0f * v);
  }
}

// ---------------- segment totals (branch-free, pipelined) ----------------
__global__ __launch_bounds__(256) void seg_tot_k(
    const int* __restrict__ evt_tag, const float* __restrict__ evt_wa,
    const float* __restrict__ evt_wd, const ushort* __restrict__ Vb,
    float* __restrict__ totWA, float* __restrict__ totWD, float* __restrict__ totP)
{
  __shared__ int srow[EPB];
  __shared__ float swa[EPB], swd[EPB], spw[EPB];
  int b = blockIdx.z, seg = blockIdx.y, chunk = blockIdx.x;
  int t = threadIdx.x;
  int e0 = b * 4096 + seg * EPB;
  if (t < EPB) {
    int tg = evt_tag[e0 + t];
    bool isk = !(tg & 0x10000);
    srow[t] = isk ? (tg & 0xFFFF) : 0;
    swa[t] = isk ? evt_wa[e0 + t] : 0.f;
    swd[t] = isk ? evt_wd[e0 + t] : 0.f;
    spw[t] = isk ? 1.f : 0.f;
  }
  __syncthreads();
  int c = chunk * 512 + t * 2;
  const ushort* vb = Vb + (size_t)b * N_ * D_ + c;
  float wa0 = 0, wa1 = 0, wd0 = 0, wd1 = 0, p0 = 0, p1 = 0;
#pragma unroll 8
  for (int e = 0; e < EPB; e++) {
    unsigned raw = *(const unsigned*)(vb + (size_t)srow[e] * D_);
    float v0 = bf2f((ushort)(raw & 0xffffu)), v1 = bf2f((ushort)(raw >> 16));
    float wa = swa[e], wd = swd[e], pw = spw[e];
    wa0 += wa * v0; wa1 += wa * v1;
    wd0 += wd * v0; wd1 += wd * v1;
    p0 += pw * v0;  p1 += pw * v1;
  }
  size_t o = ((size_t)b * SEGS + seg) * D_ + c;
  totWA[o] = wa0; totWA[o + 1] = wa1;
  totWD[o] = wd0; totWD[o + 1] = wd1;
  totP[o]  = p0;  totP[o + 1]  = p1;
}

// ---------------- cross-segment prefix/suffix precompute --------------------
__global__ __launch_bounds__(256) void seg_prefix_k(
    const float* __restrict__ totWA, const float* __restrict__ totWD,
    const float* __restrict__ totP,
    float* __restrict__ preA, float* __restrict__ prePA,
    float* __restrict__ sufD, float* __restrict__ sufPD)
{
  int b = blockIdx.y;
  int c = blockIdx.x * 256 + threadIdx.x;
  float a = 0, pa = 0;
  for (int s = 0; s < SEGS; s++) {
    size_t o = ((size_t)b * SEGS + s) * D_ + c;
    preA[o] = a; prePA[o] = pa;
    a += totWA[o]; pa += totP[o];
  }
  float d = 0, pd = 0;
  for (int s = SEGS - 1; s >= 0; s--) {
    size_t o = ((size_t)b * SEGS + s) * D_ + c;
    sufD[o] = d; sufPD[o] = pd;
    d += totWD[o]; pd += totP[o];
  }
}

// ---------------- fused asc+desc scan, LDS-staged V, branch-free accum ------
__global__ __launch_bounds__(256) void scan_both_k(
    const int* __restrict__ evt_tag, const float* __restrict__ evt_wa,
    const float* __restrict__ evt_wd, const ushort* __restrict__ Vb,
    const float* __restrict__ preA, const float* __restrict__ prePA,
    const float* __restrict__ sufD, const float* __restrict__ sufPD,
    float* AVpart, ushort* __restrict__ AVb)
{
  __shared__ ushort Vt[EPB * CW];        // 32 KB: event-major V tile
  __shared__ int sisq[EPB], sidx[EPB];
  __shared__ float skwa[EPB], skwd[EPB], sqwa[EPB], sqwd[EPB], spk[EPB];
  int b = blockIdx.z, seg = blockIdx.y, chunk = blockIdx.x;
  int t = threadIdx.x;
  int e0 = b * 4096 + seg * EPB;
  if (t < EPB) {
    int tg = evt_tag[e0 + t];
    bool isq = (tg & 0x10000) != 0;
    float wa = evt_wa[e0 + t], wd = evt_wd[e0 + t];
    sisq[t] = isq; sidx[t] = isq ? (tg & 0xFFFF) : 0;
    skwa[t] = isq ? 0.f : wa;  sqwa[t] = wa;
    skwd[t] = isq ? 0.f : wd;  sqwd[t] = wd;
    spk[t]  = isq ? 0.f : 1.f;
  }
  __syncthreads();
  int c0 = chunk * CW;
  const ushort* vbase = Vb + (size_t)b * N_ * D_ + c0;
  // srow for keys is sidx? no: sidx holds query idx; need key row for staging:
  // reload tag rows for staging (keys only; queries stage row 0 harmlessly)
  __shared__ int srow[EPB];
  if (t < EPB) {
    int tg = evt_tag[e0 + t];
    srow[t] = (tg & 0x10000) ? 0 : (tg & 0xFFFF);
  }
  __syncthreads();
#pragma unroll
  for (int r = 0; r < 8; r++) {
    int li = r * 256 + t;
    int e = li >> 5, ch = li & 31;
    gload16(vbase + (size_t)srow[e] * D_ + ch * 8, (char*)Vt + li * 16);
  }
  __syncthreads();

  int cth = c0 + t;
  size_t po = ((size_t)b * SEGS + seg) * D_ + cth;
  float* AVrow = AVpart + (size_t)b * N_ * D_ + cth;
  ushort* AVbrow = AVb + (size_t)b * N_ * D_ + cth;

  // ascending: low side (tk <= tq): 0.9*(Plow - e^{-2tq} * sum e^{2tk} V)
  {
    float s = preA[po], p = prePA[po];
#pragma unroll 4
    for (int e = 0; e < EPB; e++) {
      float v = bf2f(Vt[e * CW + t]);
      if (sisq[e]) AVrow[(size_t)sidx[e] * D_] = 0.9f * (p - sqwa[e] * s);
      s += skwa[e] * v; p += spk[e] * v;
    }
  }
  // descending: high side (tk > tq): 0.9*(Phigh + e^{2tq} * sum e^{-2tk} V)
  {
    float s = sufD[po], p = sufPD[po];
#pragma unroll 4
    for (int e = EPB - 1; e >= 0; e--) {
      float v = bf2f(Vt[e * CW + t]);
      if (sisq[e]) {
        size_t o = (size_t)sidx[e] * D_;
        AVbrow[o] = f2bf(AVrow[o] + 0.9f * (p + sqwd[e] * s));
      }
      s += skwd[e] * v; p += spk[e] * v;
    }
  }
}

extern "C" void kernel_launch(void* const* d_in, const int* in_sizes, int n_in,
                              void* d_out, int out_size, void* d_ws, size_t ws_size,
                              hipStream_t stream) {
  (void)in_sizes; (void)n_in; (void)out_size; (void)ws_size;
  const float* x  = (const float*)d_in[0];
  const float* Wq = (const float*)d_in[1];
  const float* gq = (const float*)d_in[2];
  const float* bq = (const float*)d_in[3];
  const float* mq = (const float*)d_in[4];
  const float* vq = (const float*)d_in[5];
  const float* Wk = (const float*)d_in[6];
  const float* gk = (const float*)d_in[7];
  const float* bk = (const float*)d_in[8];
  const float* mk = (const float*)d_in[9];
  const float* vk = (const float*)d_in[10];
  const float* Wv = (const float*)d_in[11];
  const float* gv = (const float*)d_in[12];
  const float* bv = (const float*)d_in[13];
  const float* mv = (const float*)d_in[14];
  const float* vv = (const float*)d_in[15];
  const float* Wo = (const float*)d_in[16];
  const float* bo = (const float*)d_in[17];

  char* p = (char*)d_ws;
  auto alloc = [&](size_t n) { char* r = p; p += n; return r; };
  ushort* x16  = (ushort*)alloc((size_t)M_ * D_ * 2);
  ushort* Vb   = (ushort*)alloc((size_t)M_ * D_ * 2);
  ushort* AVb  = (ushort*)alloc((size_t)M_ * D_ * 2);
  ushort* W3T  = (ushort*)alloc((size_t)3 * D_ * D_ * 2);
  ushort* WoT  = (ushort*)alloc((size_t)D_ * D_ * 2);
  float*  rsQ  = (float*)alloc((size_t)M_ * 4);
  float*  rsK  = (float*)alloc((size_t)M_ * 4);
  int*    evt_tag = (int*)alloc((size_t)B_ * 4096 * 4);
  float*  evt_wa  = (float*)alloc((size_t)B_ * 4096 * 4);
  float*  evt_wd  = (float*)alloc((size_t)B_ * 4096 * 4);
  float*  totWA   = (float*)alloc((size_t)B_ * SEGS * D_ * 4);
  float*  totWD   = (float*)alloc((size_t)B_ * SEGS * D_ * 4);
  float*  totP    = (float*)alloc((size_t)B_ * SEGS * D_ * 4);
  float*  preA    = (float*)alloc((size_t)B_ * SEGS * D_ * 4);
  float*  prePA   = (float*)alloc((size_t)B_ * SEGS * D_ * 4);
  float*  sufD    = (float*)alloc((size_t)B_ * SEGS * D_ * 4);
  float*  sufPD   = (float*)alloc((size_t)B_ * SEGS * D_ * 4);

  hipMemsetAsync(rsQ, 0, (size_t)2 * M_ * 4, stream);

  conv_x_k<<<(M_ * D_) / 1024, 256, 0, stream>>>((const float4*)x, (ushort4*)x16);
  dim3 tb(32, 8), tg(32, 32, 4);
  transpose_k<<<tg, tb, 0, stream>>>(Wq, Wk, Wv, Wo, W3T, WoT);

  gemm_qkv_k<<<3072, 256, 0, stream>>>(x16, W3T, gq, bq, mq, vq,
                                       gk, bk, mk, vk, gv, bv, mv, vv,
                                       rsQ, rsK, Vb);

  rank_events_k<<<dim3(32, B_), 256, 0, stream>>>(rsQ, rsK, evt_tag, evt_wa, evt_wd);

  seg_tot_k<<<dim3(2, SEGS, B_), 256, 0, stream>>>(evt_tag, evt_wa, evt_wd, Vb,
                                                   totWA, totWD, totP);
  seg_prefix_k<<<dim3(D_ / 256, B_), 256, 0, stream>>>(totWA, totWD, totP,
                                                       preA, prePA, sufD, sufPD);
  scan_both_k<<<dim3(D_ / CW, SEGS, B_), 256, 0, stream>>>(
      evt_tag, evt_wa, evt_wd, Vb, preA, prePA, sufD, sufPD, (float*)d_out, AVb);

  gemm_out_k<<<1024, 256, 0, stream>>>(AVb, WoT, (float*)d_out, bo);
}